// Round 8
// baseline (297.734 us; speedup 1.0000x reference)
//
#include <hip/hip_runtime.h>
#include <hip/hip_bf16.h>
#include <stdint.h>

#define NTOK 4096
#define DM   512
#define HD   2048
#define NE   8
#define NTILE_MAX 72   // 8192/128 + 8 partial tiles

typedef __bf16 bf16x8 __attribute__((ext_vector_type(8)));
typedef float  f32x4  __attribute__((ext_vector_type(4)));

__device__ __forceinline__ unsigned short f2bf(float f) {
  unsigned int u = __float_as_uint(f);
  u += 0x7FFF + ((u >> 16) & 1);   // RTNE
  return (unsigned short)(u >> 16);
}

__device__ __forceinline__ float gelu_fast(float x) {
  float s = 1.5957691216f * (x + 0.044715f * x * x * x);
  return x / (1.f + __expf(-s));
}

__device__ __forceinline__ void gload_lds16(const void* g, void* l) {
  __builtin_amdgcn_global_load_lds(
      (__attribute__((address_space(1))) const void*)g,
      (__attribute__((address_space(3))) void*)l,
      16, 0, 0);
}

// ---------- W[e][K][N] fp32 -> WT[e][N][K] bf16 (tiled transpose) ----------
template<int K, int N>
__global__ __launch_bounds__(256) void transw_kernel(
    const float* __restrict__ in, unsigned short* __restrict__ out) {
  __shared__ float tile[32][33];
  const int tpe = (K / 32) * (N / 32);
  int e   = blockIdx.x / tpe;
  int rem = blockIdx.x % tpe;
  int kt  = rem / (N / 32), nt = rem % (N / 32);
  int tx  = threadIdx.x & 31, ty = threadIdx.x >> 5;
  const float* src = in + ((size_t)e * K + kt * 32) * N + (size_t)nt * 32;
  #pragma unroll
  for (int i = 0; i < 4; i++) {
    int r = ty + i * 8;
    tile[r][tx] = src[(size_t)r * N + tx];
  }
  __syncthreads();
  unsigned short* dst = out + ((size_t)e * N + nt * 32) * K + (size_t)kt * 32;
  #pragma unroll
  for (int i = 0; i < 4; i++) {
    int rr = ty + i * 8;
    dst[(size_t)rr * K + tx] = f2bf(tile[tx][rr]);
  }
}

// ---------- gate ----------
__global__ __launch_bounds__(256) void gate_kernel(
    const float* __restrict__ inp, const float* __restrict__ gw,
    const float* __restrict__ gb, int* __restrict__ eidx,
    float* __restrict__ wgtA) {
  int tok = blockIdx.x * 4 + (threadIdx.x >> 6);
  int l   = threadIdx.x & 63;
  const float* x = inp + (size_t)tok * DM;
  float acc[NE];
  #pragma unroll
  for (int e = 0; e < NE; e++) acc[e] = 0.f;
  #pragma unroll
  for (int j = 0; j < DM / 64; j++) {
    int d = j * 64 + l;
    float xv = x[d];
    const float* g = gw + (size_t)d * NE;
    #pragma unroll
    for (int e = 0; e < NE; e++) acc[e] += xv * g[e];
  }
  #pragma unroll
  for (int off = 32; off >= 1; off >>= 1) {
    #pragma unroll
    for (int e = 0; e < NE; e++) acc[e] += __shfl_xor(acc[e], off, 64);
  }
  if (l == 0) {
    float lg[NE];
    #pragma unroll
    for (int e = 0; e < NE; e++) lg[e] = acc[e] + gb[e];
    int i0 = 0;
    #pragma unroll
    for (int e = 1; e < NE; e++) if (lg[e] > lg[i0]) i0 = e;
    int i1 = (i0 == 0) ? 1 : 0;
    #pragma unroll
    for (int e = 0; e < NE; e++) if (e != i0 && lg[e] > lg[i1]) i1 = e;
    float ev = expf(lg[i1] - lg[i0]);
    float w0 = 1.f / (1.f + ev);
    float w1 = ev * w0;
    wgtA[tok * 2]     = w0;
    wgtA[tok * 2 + 1] = w1;
    eidx[tok * 2]     = i0;
    eidx[tok * 2 + 1] = i1;
  }
}

// ---------- build per-expert entry lists ----------
__global__ __launch_bounds__(256) void build_lists(
    const int* __restrict__ eidx, int* __restrict__ lists,
    int* __restrict__ counts) {
  __shared__ int wsums[4];
  __shared__ int base;
  const int e = blockIdx.x;
  const int t = threadIdx.x;
  const int lane = t & 63, w = t >> 6;
  if (t == 0) base = 0;
  __syncthreads();
  for (int it = 0; it < 2 * NTOK / 256; ++it) {
    int i = it * 256 + t;
    int match = (eidx[i] == e) ? 1 : 0;
    unsigned long long b = __ballot(match);
    int wsum = __popcll(b);
    int lpre = __popcll(b & ((1ull << lane) - 1ull));
    if (lane == 0) wsums[w] = wsum;
    __syncthreads();
    int wpre = 0;
    #pragma unroll
    for (int k = 0; k < 4; k++) if (k < w) wpre += wsums[k];
    int tot = wsums[0] + wsums[1] + wsums[2] + wsums[3];
    if (match) lists[e * NTOK + base + wpre + lpre] = i;
    __syncthreads();
    if (t == 0) base += tot;
    __syncthreads();
  }
  if (t == 0) counts[e] = base;
}

// ---------- plan_tiles: flat tile table (e, row0, end) for 128-row tiles ----------
__global__ void plan_tiles(const int* __restrict__ counts,
                           int* __restrict__ tile_e, int* __restrict__ tile_row,
                           int* __restrict__ tile_end, int* __restrict__ ntiles) {
  if (threadIdx.x != 0) return;
  int off = 0, nt = 0;
  for (int e = 0; e < NE; e++) {
    int cnt = counts[e];
    int n = (cnt + 127) >> 7;
    for (int rt = 0; rt < n; rt++) {
      tile_e[nt] = e; tile_row[nt] = off + rt * 128; tile_end[nt] = off + cnt; nt++;
    }
    off += cnt;
  }
  ntiles[0] = nt;
}

// ---------- gatherX: expert-sorted X (fp32 -> bf16) + sortidx ----------
__global__ __launch_bounds__(512) void gatherX(
    const float* __restrict__ inp, const int* __restrict__ lists,
    const int* __restrict__ counts, unsigned short* __restrict__ Xg,
    int* __restrict__ sortidx) {
  const int b = blockIdx.x;
  const int e = b >> 5, lt = b & 31;
  const int cnt = counts[e];
  int off = 0;
  #pragma unroll
  for (int i = 0; i < NE; i++) if (i < e) off += counts[i];
  const int t = threadIdx.x;
  const int r = t >> 2, q = t & 3;
  const int local = lt * 128 + r;
  if (local >= cnt) return;
  const int entry = lists[e * NTOK + local];
  const int tok = entry >> 1;
  const int gpos = off + local;
  if (q == 0) sortidx[gpos] = entry;
  const float* src = inp + (size_t)tok * DM + q * 128;
  unsigned short* dst = Xg + (size_t)gpos * DM + q * 128;
  #pragma unroll
  for (int j = 0; j < 16; j++) {
    f32x4 v0 = ((const f32x4*)src)[2 * j], v1 = ((const f32x4*)src)[2 * j + 1];
    union { unsigned short s[8]; uint4 u; } o;
    #pragma unroll
    for (int k = 0; k < 4; k++) { o.s[k] = f2bf(v0[k]); o.s[4 + k] = f2bf(v1[k]); }
    ((uint4*)dst)[j] = o.u;
  }
}

// ---------- compact-grid GEMM: 128x128 tile, BK=64, 4 waves (R4 geometry) ----------
// Tile table (no dead rt), bijective XCD swizzle, T2 both-sides swizzle, 2-barrier loop.
template<int KDIM, int NDIM, bool IS_L1, int KSPLIT, int CT>
__global__ __launch_bounds__(256) void moe_gemm(
    const unsigned short* __restrict__ A,      // [8192][KDIM] bf16 (sorted rows)
    const unsigned short* __restrict__ WT,     // [E][NDIM][KDIM] bf16
    const float* __restrict__ bias,            // [E][NDIM]
    const int* __restrict__ tile_e, const int* __restrict__ tile_row,
    const int* __restrict__ tile_end, const int* __restrict__ ntiles,
    const float* __restrict__ wgtA,            // [2*NTOK]
    const int* __restrict__ sortidx,           // [8192]
    unsigned short* __restrict__ Hout,
    float* __restrict__ Out) {
  __shared__ unsigned short ldsA[128 * 64];
  __shared__ unsigned short ldsB[128 * 64];

  // bijective XCD swizzle: hardware bid -> logical wg (nwg % 8 == 0)
  const int nwg = gridDim.x;
  const int logical = (blockIdx.x % 8) * (nwg / 8) + blockIdx.x / 8;
  const int ct  = logical % CT;
  const int r1  = logical / CT;
  const int ks  = r1 % KSPLIT;
  const int t_  = r1 / KSPLIT;
  if (t_ >= ntiles[0]) return;
  const int e    = tile_e[t_];
  const int row0 = tile_row[t_];
  const int rend = tile_end[t_];

  const int KCH = KDIM / KSPLIT;               // 512 both layers
  const int NKT = KCH / 64;                    // 8

  const int t = threadIdx.x;
  const int lane = t & 63;
  const int wid  = t >> 6;
  const int wr = wid >> 1, wc = wid & 1;
  const int rowsel = t >> 3;                   // 0..31
  const int colsel = (t & 7) ^ (rowsel & 7);   // inverse-swizzled source slot

  const unsigned short* aptr[4];
  const unsigned short* bptr[4];
  #pragma unroll
  for (int i = 0; i < 4; i++) {
    int grow = row0 + i * 32 + rowsel;
    grow = grow < 2 * NTOK ? grow : 2 * NTOK - 1;
    aptr[i] = A + (long)grow * KDIM + ks * KCH + colsel * 8;
    int brow = ct * 128 + i * 32 + rowsel;
    bptr[i] = WT + ((long)e * NDIM + brow) * KDIM + ks * KCH + colsel * 8;
  }

  f32x4 acc[4][4] = {};

  for (int kt = 0; kt < NKT; ++kt) {
    #pragma unroll
    for (int i = 0; i < 4; i++) {
      gload_lds16(aptr[i] + kt * 64, (char*)ldsA + i * 4096 + wid * 1024);
      gload_lds16(bptr[i] + kt * 64, (char*)ldsB + i * 4096 + wid * 1024);
    }
    __syncthreads();
    #pragma unroll
    for (int kk = 0; kk < 2; ++kk) {
      bf16x8 a[4], b[4];
      int ko = kk * 32 + (lane >> 4) * 8;
      #pragma unroll
      for (int m = 0; m < 4; m++) {
        int ra = wr * 64 + m * 16 + (lane & 15);
        a[m] = *(const bf16x8*)&ldsA[ra * 64 + (ko ^ ((ra & 7) << 3))];
      }
      #pragma unroll
      for (int n = 0; n < 4; n++) {
        int rb = wc * 64 + n * 16 + (lane & 15);
        b[n] = *(const bf16x8*)&ldsB[rb * 64 + (ko ^ ((rb & 7) << 3))];
      }
      #pragma unroll
      for (int m = 0; m < 4; m++)
        #pragma unroll
        for (int n = 0; n < 4; n++)
          acc[m][n] = __builtin_amdgcn_mfma_f32_16x16x32_bf16(a[m], b[n], acc[m][n], 0, 0, 0);
    }
    __syncthreads();
  }

  // epilogue
  #pragma unroll
  for (int m = 0; m < 4; m++) {
    int rbase = wr * 64 + m * 16 + (lane >> 4) * 4;
    #pragma unroll
    for (int n = 0; n < 4; n++) {
      int col = ct * 128 + wc * 64 + n * 16 + (lane & 15);
      float bv = (KSPLIT == 1 || ks == 0) ? bias[e * NDIM + col] : 0.f;
      #pragma unroll
      for (int r = 0; r < 4; r++) {
        int grow = row0 + rbase + r;
        if (grow >= rend) continue;
        float v = acc[m][n][r] + bv;
        if (IS_L1) {
          Hout[(size_t)grow * NDIM + col] = f2bf(gelu_fast(v));
        } else {
          int ent = sortidx[grow];
          atomicAdd(Out + (size_t)(ent >> 1) * NDIM + col, v * wgtA[ent]);
        }
      }
    }
  }
}

// ---------- diagnostic probe: identical K-loop, L2-resident 512KB source window ----------
__global__ __launch_bounds__(256) void probe_gemm(
    const unsigned short* __restrict__ Xg, float* __restrict__ probe_out) {
  __shared__ unsigned short ldsA[128 * 64];
  __shared__ unsigned short ldsB[128 * 64];
  const int t = threadIdx.x;
  const int lane = t & 63;
  const int wid  = t >> 6;
  const int wr = wid >> 1, wc = wid & 1;
  const int rowsel = t >> 3;
  const int colsel = (t & 7) ^ (rowsel & 7);

  f32x4 acc[4][4] = {};
  for (int kt = 0; kt < 8; ++kt) {
    #pragma unroll
    for (int i = 0; i < 4; i++) {
      int aoff = (((i * 32 + rowsel) * 64) + kt * 8192 + colsel * 8) & 131071;
      int boff = ((((i * 32 + rowsel) ^ 17) * 64) + kt * 8192 + colsel * 8) & 131071;
      gload_lds16(Xg + aoff,          (char*)ldsA + i * 4096 + wid * 1024);
      gload_lds16(Xg + 131072 + boff, (char*)ldsB + i * 4096 + wid * 1024);
    }
    __syncthreads();
    #pragma unroll
    for (int kk = 0; kk < 2; ++kk) {
      bf16x8 a[4], b[4];
      int ko = kk * 32 + (lane >> 4) * 8;
      #pragma unroll
      for (int m = 0; m < 4; m++) {
        int ra = wr * 64 + m * 16 + (lane & 15);
        a[m] = *(const bf16x8*)&ldsA[ra * 64 + (ko ^ ((ra & 7) << 3))];
      }
      #pragma unroll
      for (int n = 0; n < 4; n++) {
        int rb = wc * 64 + n * 16 + (lane & 15);
        b[n] = *(const bf16x8*)&ldsB[rb * 64 + (ko ^ ((rb & 7) << 3))];
      }
      #pragma unroll
      for (int m = 0; m < 4; m++)
        #pragma unroll
        for (int n = 0; n < 4; n++)
          acc[m][n] = __builtin_amdgcn_mfma_f32_16x16x32_bf16(a[m], b[n], acc[m][n], 0, 0, 0);
    }
    __syncthreads();
  }
  float s = 0.f;
  #pragma unroll
  for (int m = 0; m < 4; m++)
    #pragma unroll
    for (int n = 0; n < 4; n++)
      #pragma unroll
      for (int r = 0; r < 4; r++) s += acc[m][n][r];
  probe_out[(blockIdx.x & 63) * 256 + t] = s;   // unread scratch
}

extern "C" void kernel_launch(void* const* d_in, const int* in_sizes, int n_in,
                              void* d_out, int out_size, void* d_ws, size_t ws_size,
                              hipStream_t stream) {
  const float* inp = (const float*)d_in[0];
  const float* gw  = (const float*)d_in[1];
  const float* gb  = (const float*)d_in[2];
  const float* w1  = (const float*)d_in[3];
  const float* b1  = (const float*)d_in[4];
  const float* w2  = (const float*)d_in[5];
  const float* b2  = (const float*)d_in[6];
  float* out = (float*)d_out;

  char* ws = (char*)d_ws;
  unsigned short* W1T  = (unsigned short*)(ws + 0);          // 16 MiB [8][2048][512]
  unsigned short* W2T  = (unsigned short*)(ws + 16777216);   // 16 MiB [8][512][2048]
  unsigned short* Xg   = (unsigned short*)(ws + 33554432);   //  8 MiB [8192][512] sorted
  unsigned short* Hs   = (unsigned short*)(ws + 41943040);   // 32 MiB [8192][2048] sorted
  int*   lists    = (int*)  (ws + 75497472);                 // [8][4096]
  float* wgtA     = (float*)(ws + 75628544);                 // [8192]
  int*   eidx     = (int*)  (ws + 75661312);                 // [8192]
  int*   sortidx  = (int*)  (ws + 75694080);                 // [8192]
  int*   counts   = (int*)  (ws + 75726848);                 // [8]
  int*   ntiles   = (int*)  (ws + 75726880);                 // [1]
  int*   tile_e   = (int*)  (ws + 75726912);                 // [72]
  int*   tile_row = (int*)  (ws + 75727232);                 // [72]
  int*   tile_end = (int*)  (ws + 75727552);                 // [72]
  float* probe_out= (float*)(ws + 75727872);                 // 64 KiB scratch

  hipMemsetAsync(out, 0, (size_t)NTOK * DM * sizeof(float), stream);

  transw_kernel<DM, HD><<<NE * (DM / 32) * (HD / 32), 256, 0, stream>>>(w1, W1T);
  transw_kernel<HD, DM><<<NE * (HD / 32) * (DM / 32), 256, 0, stream>>>(w2, W2T);
  gate_kernel<<<NTOK / 4, 256, 0, stream>>>(inp, gw, gb, eidx, wgtA);
  build_lists<<<NE, 256, 0, stream>>>(eidx, lists, counts);
  plan_tiles<<<1, 64, 0, stream>>>(counts, tile_e, tile_row, tile_end, ntiles);
  gatherX<<<NE * 32, 512, 0, stream>>>(inp, lists, counts, Xg, sortidx);
  // L1: 72 tiles x 16 ct = 1152 blocks (144 per XCD, swizzled)
  moe_gemm<DM, HD, true, 1, 16><<<NTILE_MAX * 16, 256, 0, stream>>>(
      Xg, W1T, b1, tile_e, tile_row, tile_end, ntiles, wgtA, sortidx, Hs, nullptr);
  // L2: 72 tiles x 4 ks x 4 ct = 1152 blocks
  moe_gemm<HD, DM, false, 4, 4><<<NTILE_MAX * 4 * 4, 256, 0, stream>>>(
      Hs, W2T, b2, tile_e, tile_row, tile_end, ntiles, wgtA, sortidx, nullptr, out);
  // diagnostic: same structure, L2-resident sources
  probe_gemm<<<1024, 256, 0, stream>>>(Xg, probe_out);
}

// Round 9
// 165.917 us; speedup vs baseline: 1.7945x; 1.7945x over previous
//
#include <hip/hip_runtime.h>
#include <hip/hip_bf16.h>
#include <stdint.h>

#define NTOK 4096
#define DM   512
#define HD   2048
#define NE   8

typedef __bf16 bf16x8 __attribute__((ext_vector_type(8)));
typedef float  f32x4  __attribute__((ext_vector_type(4)));

__device__ __forceinline__ unsigned short f2bf(float f) {
  unsigned int u = __float_as_uint(f);
  u += 0x7FFF + ((u >> 16) & 1);   // RTNE
  return (unsigned short)(u >> 16);
}

__device__ __forceinline__ float gelu_fast(float x) {
  float s = 1.5957691216f * (x + 0.044715f * x * x * x);
  return x / (1.f + __expf(-s));
}

__device__ __forceinline__ void gload_lds16(const void* g, void* l) {
  __builtin_amdgcn_global_load_lds(
      (__attribute__((address_space(1))) const void*)g,
      (__attribute__((address_space(3))) void*)l,
      16, 0, 0);
}

// ---------- X: fp32 -> bf16 ----------
__global__ __launch_bounds__(256) void convx_kernel(
    const float* __restrict__ in, unsigned short* __restrict__ out, int n8) {
  int i = blockIdx.x * 256 + threadIdx.x;
  if (i >= n8) return;
  const f32x4* p = (const f32x4*)(in + (size_t)i * 8);
  f32x4 v0 = p[0], v1 = p[1];
  union { unsigned short s[8]; uint4 u; } o;
  #pragma unroll
  for (int j = 0; j < 4; j++) { o.s[j] = f2bf(v0[j]); o.s[4 + j] = f2bf(v1[j]); }
  *(uint4*)(out + (size_t)i * 8) = o.u;
}

// ---------- W[e][K][N] fp32 -> WT[e][N][K] bf16 (tiled transpose) ----------
template<int K, int N>
__global__ __launch_bounds__(256) void transw_kernel(
    const float* __restrict__ in, unsigned short* __restrict__ out) {
  __shared__ float tile[32][33];
  const int tpe = (K / 32) * (N / 32);
  int e   = blockIdx.x / tpe;
  int rem = blockIdx.x % tpe;
  int kt  = rem / (N / 32), nt = rem % (N / 32);
  int tx  = threadIdx.x & 31, ty = threadIdx.x >> 5;
  const float* src = in + ((size_t)e * K + kt * 32) * N + (size_t)nt * 32;
  #pragma unroll
  for (int i = 0; i < 4; i++) {
    int r = ty + i * 8;
    tile[r][tx] = src[(size_t)r * N + tx];
  }
  __syncthreads();
  unsigned short* dst = out + ((size_t)e * N + nt * 32) * K + (size_t)kt * 32;
  #pragma unroll
  for (int i = 0; i < 4; i++) {
    int rr = ty + i * 8;
    dst[(size_t)rr * K + tx] = f2bf(tile[tx][rr]);
  }
}

// ---------- gate: fp32 logits, top-2, softmax weights, expert ids (NO atomics) ----------
__global__ __launch_bounds__(256) void gate_kernel(
    const float* __restrict__ inp, const float* __restrict__ gw,
    const float* __restrict__ gb, int* __restrict__ eidx,
    float* __restrict__ wgtA) {
  int tok = blockIdx.x * 4 + (threadIdx.x >> 6);
  int l   = threadIdx.x & 63;
  const float* x = inp + (size_t)tok * DM;
  float acc[NE];
  #pragma unroll
  for (int e = 0; e < NE; e++) acc[e] = 0.f;
  #pragma unroll
  for (int j = 0; j < DM / 64; j++) {
    int d = j * 64 + l;
    float xv = x[d];
    const float* g = gw + (size_t)d * NE;
    #pragma unroll
    for (int e = 0; e < NE; e++) acc[e] += xv * g[e];
  }
  #pragma unroll
  for (int off = 32; off >= 1; off >>= 1) {
    #pragma unroll
    for (int e = 0; e < NE; e++) acc[e] += __shfl_xor(acc[e], off, 64);
  }
  if (l == 0) {
    float lg[NE];
    #pragma unroll
    for (int e = 0; e < NE; e++) lg[e] = acc[e] + gb[e];
    int i0 = 0;
    #pragma unroll
    for (int e = 1; e < NE; e++) if (lg[e] > lg[i0]) i0 = e;
    int i1 = (i0 == 0) ? 1 : 0;
    #pragma unroll
    for (int e = 0; e < NE; e++) if (e != i0 && lg[e] > lg[i1]) i1 = e;
    float ev = expf(lg[i1] - lg[i0]);
    float w0 = 1.f / (1.f + ev);
    float w1 = ev * w0;
    wgtA[tok * 2]     = w0;
    wgtA[tok * 2 + 1] = w1;
    eidx[tok * 2]     = i0;
    eidx[tok * 2 + 1] = i1;
  }
}

// ---------- build per-expert entry lists: 1 block per expert, ballot prefix scan ----------
__global__ __launch_bounds__(256) void build_lists(
    const int* __restrict__ eidx, int* __restrict__ lists,
    int* __restrict__ counts) {
  __shared__ int wsums[4];
  __shared__ int base;
  const int e = blockIdx.x;
  const int t = threadIdx.x;
  const int lane = t & 63, w = t >> 6;
  if (t == 0) base = 0;
  __syncthreads();
  for (int it = 0; it < 2 * NTOK / 256; ++it) {
    int i = it * 256 + t;
    int match = (eidx[i] == e) ? 1 : 0;
    unsigned long long b = __ballot(match);
    int wsum = __popcll(b);
    int lpre = __popcll(b & ((1ull << lane) - 1ull));
    if (lane == 0) wsums[w] = wsum;
    __syncthreads();
    int wpre = 0;
    #pragma unroll
    for (int k = 0; k < 4; k++) if (k < w) wpre += wsums[k];
    int tot = wsums[0] + wsums[1] + wsums[2] + wsums[3];
    if (match) lists[e * NTOK + base + wpre + lpre] = i;
    __syncthreads();
    if (t == 0) base += tot;
    __syncthreads();
  }
  if (t == 0) counts[e] = base;
}

// ---------- gathered GEMM: 128x128 tile, BK=128, 4 waves, 16x16x32 bf16 MFMA ----------
// R4 structure (2-barrier single-buffer loop, ldsE gather, natural block order)
// with BK doubled 64->128: half the barrier-drain stalls at identical staged bytes.
// T2 XOR swizzle both-sides (16B-chunk granularity, 16 chunks/row).
template<int KDIM, int NDIM, bool IS_L1>
__global__ __launch_bounds__(256) void moe_gemm(
    const unsigned short* __restrict__ A,
    const unsigned short* __restrict__ WT,     // [E][NDIM][KDIM] bf16
    const float* __restrict__ bias,            // [E][NDIM]
    const int* __restrict__ lists,             // [E][NTOK]
    const int* __restrict__ counts,            // [E]
    const float* __restrict__ wgtA,            // [2*NTOK]
    unsigned short* __restrict__ Hout,
    float* __restrict__ Out) {
  __shared__ unsigned short ldsA[128 * 128];   // 32 KiB
  __shared__ unsigned short ldsB[128 * 128];   // 32 KiB
  __shared__ int ldsE[128];

  const int CT    = NDIM / 128;
  const int per_e = 32 * CT;
  const int e   = blockIdx.x / per_e;
  const int rem = blockIdx.x % per_e;
  const int rt  = rem / CT;
  const int ct  = rem % CT;
  const int cnt = counts[e];
  if (rt * 128 >= cnt) return;

  const int t = threadIdx.x;
  if (t < 128) {
    int rg = rt * 128 + t;
    ldsE[t] = lists[e * NTOK + (rg < cnt ? rg : cnt - 1)];
  }
  __syncthreads();

  const int lane = t & 63;
  const int wid  = t >> 6;
  const int wr = wid >> 1, wc = wid & 1;
  const int rowsel = t >> 4;                   // 0..15: row within each 16-row issue group
  const int chunk  = (t & 15) ^ (rowsel & 7);  // inverse-swizzled 16B source chunk (issue-invariant)

  const unsigned short* aptr[8];
  const unsigned short* bptr[8];
  #pragma unroll
  for (int i = 0; i < 8; i++) {
    int rl = i * 16 + rowsel;
    int entry = ldsE[rl];
    long arow = IS_L1 ? (entry >> 1) : entry;
    aptr[i] = A + arow * (long)KDIM + chunk * 8;
    bptr[i] = WT + ((long)e * NDIM + ct * 128 + rl) * KDIM + chunk * 8;
  }

  f32x4 acc[4][4] = {};

  const int NKT = KDIM / 128;                  // 4 (L1) or 16 (L2)
  for (int kt = 0; kt < NKT; ++kt) {
    #pragma unroll
    for (int i = 0; i < 8; i++) {
      gload_lds16(aptr[i] + kt * 128, (char*)ldsA + i * 4096 + wid * 1024);
      gload_lds16(bptr[i] + kt * 128, (char*)ldsB + i * 4096 + wid * 1024);
    }
    __syncthreads();                           // compiler drains vmcnt
    #pragma unroll
    for (int kk = 0; kk < 4; ++kk) {
      bf16x8 a[4], b[4];
      int ko = kk * 32 + (lane >> 4) * 8;
      #pragma unroll
      for (int m = 0; m < 4; m++) {
        int ra = wr * 64 + m * 16 + (lane & 15);
        a[m] = *(const bf16x8*)&ldsA[ra * 128 + (ko ^ ((ra & 7) << 3))];
      }
      #pragma unroll
      for (int n = 0; n < 4; n++) {
        int rb = wc * 64 + n * 16 + (lane & 15);
        b[n] = *(const bf16x8*)&ldsB[rb * 128 + (ko ^ ((rb & 7) << 3))];
      }
      #pragma unroll
      for (int m = 0; m < 4; m++)
        #pragma unroll
        for (int n = 0; n < 4; n++)
          acc[m][n] = __builtin_amdgcn_mfma_f32_16x16x32_bf16(a[m], b[n], acc[m][n], 0, 0, 0);
    }
    __syncthreads();
  }

  // epilogue: C/D mapping col=lane&15, row=(lane>>4)*4+reg (m89-verified)
  #pragma unroll
  for (int m = 0; m < 4; m++) {
    int rbase = wr * 64 + m * 16 + (lane >> 4) * 4;
    int ent[4];
    #pragma unroll
    for (int r = 0; r < 4; r++) ent[r] = ldsE[rbase + r];
    #pragma unroll
    for (int n = 0; n < 4; n++) {
      int col = ct * 128 + wc * 64 + n * 16 + (lane & 15);
      float bv = bias[e * NDIM + col];
      #pragma unroll
      for (int r = 0; r < 4; r++) {
        if (rt * 128 + rbase + r >= cnt) continue;
        float v = acc[m][n][r] + bv;
        if (IS_L1) {
          Hout[(size_t)ent[r] * NDIM + col] = f2bf(gelu_fast(v));
        } else {
          atomicAdd(Out + (size_t)(ent[r] >> 1) * NDIM + col, v * wgtA[ent[r]]);
        }
      }
    }
  }
}

extern "C" void kernel_launch(void* const* d_in, const int* in_sizes, int n_in,
                              void* d_out, int out_size, void* d_ws, size_t ws_size,
                              hipStream_t stream) {
  const float* inp = (const float*)d_in[0];
  const float* gw  = (const float*)d_in[1];
  const float* gb  = (const float*)d_in[2];
  const float* w1  = (const float*)d_in[3];
  const float* b1  = (const float*)d_in[4];
  const float* w2  = (const float*)d_in[5];
  const float* b2  = (const float*)d_in[6];
  float* out = (float*)d_out;

  char* ws = (char*)d_ws;
  unsigned short* Xb   = (unsigned short*)(ws + 0);          //  4 MiB: [4096][512] bf16
  unsigned short* W1T  = (unsigned short*)(ws + 4194304);    // 16 MiB: [8][2048][512] bf16
  unsigned short* W2T  = (unsigned short*)(ws + 20971520);   // 16 MiB: [8][512][2048] bf16
  unsigned short* Hbuf = (unsigned short*)(ws + 37748736);   // 32 MiB: [8192][2048] bf16
  int*   lists  = (int*)  (ws + 71303168);                   // [8][4096] int
  float* wgtA   = (float*)(ws + 71434240);                   // [8192] f32
  int*   counts = (int*)  (ws + 71467008);                   // [8] int
  int*   eidx   = (int*)  (ws + 71467072);                   // [8192] int

  hipMemsetAsync(out, 0, (size_t)NTOK * DM * sizeof(float), stream);

  convx_kernel<<<NTOK * DM / 8 / 256, 256, 0, stream>>>(inp, Xb, NTOK * DM / 8);
  transw_kernel<DM, HD><<<NE * (DM / 32) * (HD / 32), 256, 0, stream>>>(w1, W1T);
  transw_kernel<HD, DM><<<NE * (HD / 32) * (DM / 32), 256, 0, stream>>>(w2, W2T);
  gate_kernel<<<NTOK / 4, 256, 0, stream>>>(inp, gw, gb, eidx, wgtA);
  build_lists<<<NE, 256, 0, stream>>>(eidx, lists, counts);
  moe_gemm<DM, HD, true ><<<NE * 32 * (HD / 128), 256, 0, stream>>>(
      Xb, W1T, b1, lists, counts, wgtA, Hbuf, nullptr);
  moe_gemm<HD, DM, false><<<NE * 32 * (DM / 128), 256, 0, stream>>>(
      Hbuf, W2T, b2, lists, counts, wgtA, nullptr, out);
}

// Round 10
// 156.950 us; speedup vs baseline: 1.8970x; 1.0571x over previous
//
#include <hip/hip_runtime.h>
#include <hip/hip_bf16.h>
#include <stdint.h>

#define NTOK 4096
#define DM   512
#define HD   2048
#define NE   8

typedef __bf16 bf16x8 __attribute__((ext_vector_type(8)));
typedef float  f32x4  __attribute__((ext_vector_type(4)));

__device__ __forceinline__ unsigned short f2bf(float f) {
  unsigned int u = __float_as_uint(f);
  u += 0x7FFF + ((u >> 16) & 1);   // RTNE
  return (unsigned short)(u >> 16);
}

__device__ __forceinline__ float gelu_fast(float x) {
  float s = 1.5957691216f * (x + 0.044715f * x * x * x);
  return x / (1.f + __expf(-s));
}

__device__ __forceinline__ void gload_lds16(const void* g, void* l) {
  __builtin_amdgcn_global_load_lds(
      (__attribute__((address_space(1))) const void*)g,
      (__attribute__((address_space(3))) void*)l,
      16, 0, 0);
}

// ---------- X: fp32 -> bf16 ----------
__global__ __launch_bounds__(256) void convx_kernel(
    const float* __restrict__ in, unsigned short* __restrict__ out, int n8) {
  int i = blockIdx.x * 256 + threadIdx.x;
  if (i >= n8) return;
  const f32x4* p = (const f32x4*)(in + (size_t)i * 8);
  f32x4 v0 = p[0], v1 = p[1];
  union { unsigned short s[8]; uint4 u; } o;
  #pragma unroll
  for (int j = 0; j < 4; j++) { o.s[j] = f2bf(v0[j]); o.s[4 + j] = f2bf(v1[j]); }
  *(uint4*)(out + (size_t)i * 8) = o.u;
}

// ---------- W[e][K][N] fp32 -> WT[e][N][K] bf16 (tiled transpose) ----------
template<int K, int N>
__global__ __launch_bounds__(256) void transw_kernel(
    const float* __restrict__ in, unsigned short* __restrict__ out) {
  __shared__ float tile[32][33];
  const int tpe = (K / 32) * (N / 32);
  int e   = blockIdx.x / tpe;
  int rem = blockIdx.x % tpe;
  int kt  = rem / (N / 32), nt = rem % (N / 32);
  int tx  = threadIdx.x & 31, ty = threadIdx.x >> 5;
  const float* src = in + ((size_t)e * K + kt * 32) * N + (size_t)nt * 32;
  #pragma unroll
  for (int i = 0; i < 4; i++) {
    int r = ty + i * 8;
    tile[r][tx] = src[(size_t)r * N + tx];
  }
  __syncthreads();
  unsigned short* dst = out + ((size_t)e * N + nt * 32) * K + (size_t)kt * 32;
  #pragma unroll
  for (int i = 0; i < 4; i++) {
    int rr = ty + i * 8;
    dst[(size_t)rr * K + tx] = f2bf(tile[tx][rr]);
  }
}

// ---------- gate: fp32 logits, top-2, softmax weights, expert ids (NO atomics) ----------
__global__ __launch_bounds__(256) void gate_kernel(
    const float* __restrict__ inp, const float* __restrict__ gw,
    const float* __restrict__ gb, int* __restrict__ eidx,
    float* __restrict__ wgtA) {
  int tok = blockIdx.x * 4 + (threadIdx.x >> 6);
  int l   = threadIdx.x & 63;
  const float* x = inp + (size_t)tok * DM;
  float acc[NE];
  #pragma unroll
  for (int e = 0; e < NE; e++) acc[e] = 0.f;
  #pragma unroll
  for (int j = 0; j < DM / 64; j++) {
    int d = j * 64 + l;
    float xv = x[d];
    const float* g = gw + (size_t)d * NE;
    #pragma unroll
    for (int e = 0; e < NE; e++) acc[e] += xv * g[e];
  }
  #pragma unroll
  for (int off = 32; off >= 1; off >>= 1) {
    #pragma unroll
    for (int e = 0; e < NE; e++) acc[e] += __shfl_xor(acc[e], off, 64);
  }
  if (l == 0) {
    float lg[NE];
    #pragma unroll
    for (int e = 0; e < NE; e++) lg[e] = acc[e] + gb[e];
    int i0 = 0;
    #pragma unroll
    for (int e = 1; e < NE; e++) if (lg[e] > lg[i0]) i0 = e;
    int i1 = (i0 == 0) ? 1 : 0;
    #pragma unroll
    for (int e = 0; e < NE; e++) if (e != i0 && lg[e] > lg[i1]) i1 = e;
    float ev = expf(lg[i1] - lg[i0]);
    float w0 = 1.f / (1.f + ev);
    float w1 = ev * w0;
    wgtA[tok * 2]     = w0;
    wgtA[tok * 2 + 1] = w1;
    eidx[tok * 2]     = i0;
    eidx[tok * 2 + 1] = i1;
  }
}

// ---------- build per-expert entry lists: 1 block per expert, ballot prefix scan ----------
__global__ __launch_bounds__(256) void build_lists(
    const int* __restrict__ eidx, int* __restrict__ lists,
    int* __restrict__ counts) {
  __shared__ int wsums[4];
  __shared__ int base;
  const int e = blockIdx.x;
  const int t = threadIdx.x;
  const int lane = t & 63, w = t >> 6;
  if (t == 0) base = 0;
  __syncthreads();
  for (int it = 0; it < 2 * NTOK / 256; ++it) {
    int i = it * 256 + t;
    int match = (eidx[i] == e) ? 1 : 0;
    unsigned long long b = __ballot(match);
    int wsum = __popcll(b);
    int lpre = __popcll(b & ((1ull << lane) - 1ull));
    if (lane == 0) wsums[w] = wsum;
    __syncthreads();
    int wpre = 0;
    #pragma unroll
    for (int k = 0; k < 4; k++) if (k < w) wpre += wsums[k];
    int tot = wsums[0] + wsums[1] + wsums[2] + wsums[3];
    if (match) lists[e * NTOK + base + wpre + lpre] = i;
    __syncthreads();
    if (t == 0) base += tot;
    __syncthreads();
  }
  if (t == 0) counts[e] = base;
}

// ---------- gathered GEMM: 128x128 tile, BK=128, 4 waves, 16x16x32 bf16 MFMA ----------
// R9 structure with ONE change: expert->XCD pinning. blockIdx & 7 == expert, so each
// XCD's L2 holds only its expert's W panel (2 MB) + active A rows (~1 MB) -> L2-resident
// staging instead of L3-served (~3 TB/s wall measured R4-R9).
// Within-expert order: ct fastest (16 consecutive blocks share A rows, W_e stays hot).
template<int KDIM, int NDIM, bool IS_L1>
__global__ __launch_bounds__(256) void moe_gemm(
    const unsigned short* __restrict__ A,
    const unsigned short* __restrict__ WT,     // [E][NDIM][KDIM] bf16
    const float* __restrict__ bias,            // [E][NDIM]
    const int* __restrict__ lists,             // [E][NTOK]
    const int* __restrict__ counts,            // [E]
    const float* __restrict__ wgtA,            // [2*NTOK]
    unsigned short* __restrict__ Hout,
    float* __restrict__ Out) {
  __shared__ unsigned short ldsA[128 * 128];   // 32 KiB
  __shared__ unsigned short ldsB[128 * 128];   // 32 KiB
  __shared__ int ldsE[128];

  const int CT  = NDIM / 128;
  const int e   = blockIdx.x & 7;              // expert == XCD (HW round-robin, m09)
  const int idx = blockIdx.x >> 3;             // tile within expert, ct fastest
  const int rt  = idx / CT;
  const int ct  = idx % CT;
  const int cnt = counts[e];
  if (rt * 128 >= cnt) return;

  const int t = threadIdx.x;
  if (t < 128) {
    int rg = rt * 128 + t;
    ldsE[t] = lists[e * NTOK + (rg < cnt ? rg : cnt - 1)];
  }
  __syncthreads();

  const int lane = t & 63;
  const int wid  = t >> 6;
  const int wr = wid >> 1, wc = wid & 1;
  const int rowsel = t >> 4;                   // 0..15: row within each 16-row issue group
  const int chunk  = (t & 15) ^ (rowsel & 7);  // inverse-swizzled 16B source chunk

  const unsigned short* aptr[8];
  const unsigned short* bptr[8];
  #pragma unroll
  for (int i = 0; i < 8; i++) {
    int rl = i * 16 + rowsel;
    int entry = ldsE[rl];
    long arow = IS_L1 ? (entry >> 1) : entry;
    aptr[i] = A + arow * (long)KDIM + chunk * 8;
    bptr[i] = WT + ((long)e * NDIM + ct * 128 + rl) * KDIM + chunk * 8;
  }

  f32x4 acc[4][4] = {};

  const int NKT = KDIM / 128;                  // 4 (L1) or 16 (L2)
  for (int kt = 0; kt < NKT; ++kt) {
    #pragma unroll
    for (int i = 0; i < 8; i++) {
      gload_lds16(aptr[i] + kt * 128, (char*)ldsA + i * 4096 + wid * 1024);
      gload_lds16(bptr[i] + kt * 128, (char*)ldsB + i * 4096 + wid * 1024);
    }
    __syncthreads();                           // compiler drains vmcnt
    #pragma unroll
    for (int kk = 0; kk < 4; ++kk) {
      bf16x8 a[4], b[4];
      int ko = kk * 32 + (lane >> 4) * 8;
      #pragma unroll
      for (int m = 0; m < 4; m++) {
        int ra = wr * 64 + m * 16 + (lane & 15);
        a[m] = *(const bf16x8*)&ldsA[ra * 128 + (ko ^ ((ra & 7) << 3))];
      }
      #pragma unroll
      for (int n = 0; n < 4; n++) {
        int rb = wc * 64 + n * 16 + (lane & 15);
        b[n] = *(const bf16x8*)&ldsB[rb * 128 + (ko ^ ((rb & 7) << 3))];
      }
      #pragma unroll
      for (int m = 0; m < 4; m++)
        #pragma unroll
        for (int n = 0; n < 4; n++)
          acc[m][n] = __builtin_amdgcn_mfma_f32_16x16x32_bf16(a[m], b[n], acc[m][n], 0, 0, 0);
    }
    __syncthreads();
  }

  // epilogue: C/D mapping col=lane&15, row=(lane>>4)*4+reg (m89-verified)
  #pragma unroll
  for (int m = 0; m < 4; m++) {
    int rbase = wr * 64 + m * 16 + (lane >> 4) * 4;
    int ent[4];
    #pragma unroll
    for (int r = 0; r < 4; r++) ent[r] = ldsE[rbase + r];
    #pragma unroll
    for (int n = 0; n < 4; n++) {
      int col = ct * 128 + wc * 64 + n * 16 + (lane & 15);
      float bv = bias[e * NDIM + col];
      #pragma unroll
      for (int r = 0; r < 4; r++) {
        if (rt * 128 + rbase + r >= cnt) continue;
        float v = acc[m][n][r] + bv;
        if (IS_L1) {
          Hout[(size_t)ent[r] * NDIM + col] = f2bf(gelu_fast(v));
        } else {
          atomicAdd(Out + (size_t)(ent[r] >> 1) * NDIM + col, v * wgtA[ent[r]]);
        }
      }
    }
  }
}

extern "C" void kernel_launch(void* const* d_in, const int* in_sizes, int n_in,
                              void* d_out, int out_size, void* d_ws, size_t ws_size,
                              hipStream_t stream) {
  const float* inp = (const float*)d_in[0];
  const float* gw  = (const float*)d_in[1];
  const float* gb  = (const float*)d_in[2];
  const float* w1  = (const float*)d_in[3];
  const float* b1  = (const float*)d_in[4];
  const float* w2  = (const float*)d_in[5];
  const float* b2  = (const float*)d_in[6];
  float* out = (float*)d_out;

  char* ws = (char*)d_ws;
  unsigned short* Xb   = (unsigned short*)(ws + 0);          //  4 MiB: [4096][512] bf16
  unsigned short* W1T  = (unsigned short*)(ws + 4194304);    // 16 MiB: [8][2048][512] bf16
  unsigned short* W2T  = (unsigned short*)(ws + 20971520);   // 16 MiB: [8][512][2048] bf16
  unsigned short* Hbuf = (unsigned short*)(ws + 37748736);   // 32 MiB: [8192][2048] bf16
  int*   lists  = (int*)  (ws + 71303168);                   // [8][4096] int
  float* wgtA   = (float*)(ws + 71434240);                   // [8192] f32
  int*   counts = (int*)  (ws + 71467008);                   // [8] int
  int*   eidx   = (int*)  (ws + 71467072);                   // [8192] int

  hipMemsetAsync(out, 0, (size_t)NTOK * DM * sizeof(float), stream);

  convx_kernel<<<NTOK * DM / 8 / 256, 256, 0, stream>>>(inp, Xb, NTOK * DM / 8);
  transw_kernel<DM, HD><<<NE * (DM / 32) * (HD / 32), 256, 0, stream>>>(w1, W1T);
  transw_kernel<HD, DM><<<NE * (HD / 32) * (DM / 32), 256, 0, stream>>>(w2, W2T);
  gate_kernel<<<NTOK / 4, 256, 0, stream>>>(inp, gw, gb, eidx, wgtA);
  build_lists<<<NE, 256, 0, stream>>>(eidx, lists, counts);
  // grid = 8 XCD-pinned experts x worst-case tiles (32 rt x CT); dead tiles exit
  moe_gemm<DM, HD, true ><<<8 * 32 * (HD / 128), 256, 0, stream>>>(
      Xb, W1T, b1, lists, counts, wgtA, Hbuf, nullptr);
  moe_gemm<HD, DM, false><<<8 * 32 * (DM / 128), 256, 0, stream>>>(
      Hbuf, W2T, b2, lists, counts, wgtA, nullptr, out);
}